// Round 1
// baseline (656.643 us; speedup 1.0000x reference)
//
#include <hip/hip_runtime.h>
#include <stdint.h>

// Problem constants (B=2,S=2048,H=1024,F=4096,E=8,K=2)
#define H_DIM 1024
#define F_DIM 4096
#define E_NUM 8
#define T_NUM 4096            // B*S tokens
#define NE    8192            // K * T entries
#define BM    128
#define BN    128
#define BK    64
#define MAXTILES 72           // sum_e ceil(n_e/BM) <= NE/BM + (E-1) = 71 < 72
#define PADMAX (MAXTILES*BM)  // 9216 padded entry rows

// meta[] layout (ints)
#define M_NT  0     // ntiles
#define M_PB  1     // [8]  padded base row per expert
#define M_CNT 16    // [8]  counts
#define M_CUR 24    // [8]  scatter cursors
#define M_TE  32    // [72] tile -> expert
#define M_TR  104   // [72] tile -> row base
#define M_INTS 176

typedef float  f32x4  __attribute__((ext_vector_type(4)));
typedef short  bf16x8 __attribute__((ext_vector_type(8)));   // MFMA frag: 8 bf16 bit-patterns
typedef __bf16 b16v8  __attribute__((ext_vector_type(8)));   // for fp32->bf16 conversion
typedef unsigned short u16;
typedef u16    u16x8  __attribute__((ext_vector_type(8)));

// tanh-approx gelu (matches jax.nn.gelu approximate=True):
// 0.5*v*(1+tanh(c*(v+0.044715 v^3))) == v * sigmoid(2*c*(v+0.044715 v^3))
__device__ __forceinline__ float gelu_tanh(float v) {
  float u = 0.7978845608028654f * (v + 0.044715f * v * v * v);
  return v / (1.0f + __expf(-2.0f * u));
}

// ---------------- prep kernels ----------------

__global__ void k_init(int* tok, float* wgt, int* meta) {
  int i = blockIdx.x * 256 + threadIdx.x;
  if (i < PADMAX) { tok[i] = 0; wgt[i] = 0.f; }   // padded rows: token 0, weight 0
  if (i < E_NUM) { meta[M_CNT + i] = 0; meta[M_CUR + i] = 0; }
}

__global__ void k_count(const int* __restrict__ experts, int* meta) {
  int i = blockIdx.x * 256 + threadIdx.x;   // NE threads exactly
  int e = experts[i];
  int lane = threadIdx.x & 63;
#pragma unroll
  for (int ee = 0; ee < E_NUM; ++ee) {
    unsigned long long bm = __ballot(e == ee);
    if (e == ee && lane == __builtin_ctzll(bm))
      atomicAdd(&meta[M_CNT + ee], __popcll(bm));
  }
}

__global__ void k_plan(int* meta) {
  if (threadIdx.x != 0 || blockIdx.x != 0) return;
  int pb = 0, idx = 0;
  for (int e = 0; e < E_NUM; ++e) {
    int c = meta[M_CNT + e];
    int nt = (c + BM - 1) / BM;
    meta[M_PB + e] = pb;
    for (int t = 0; t < nt; ++t) { meta[M_TE + idx] = e; meta[M_TR + idx] = pb + t * BM; ++idx; }
    pb += nt * BM;
  }
  meta[M_NT] = idx;
}

__global__ void k_scatter(const int* __restrict__ experts, const float* __restrict__ probs,
                          int* tok, float* wgt, int* meta) {
  int i = blockIdx.x * 256 + threadIdx.x;   // NE threads
  int e = experts[i];
  int t = i & (T_NUM - 1);
  float p = probs[i];
  int lane = threadIdx.x & 63;
#pragma unroll
  for (int ee = 0; ee < E_NUM; ++ee) {
    unsigned long long bm = __ballot(e == ee);
    if (e == ee) {
      int leader = __builtin_ctzll(bm);
      int cnt = __popcll(bm);
      int base = 0;
      if (lane == leader) base = atomicAdd(&meta[M_CUR + ee], cnt);
      base = __shfl(base, leader);
      int rank = __popcll(bm & ((1ull << lane) - 1ull));
      int pos = meta[M_PB + ee] + base + rank;
      tok[pos] = t;
      wgt[pos] = p;
    }
  }
}

// x fp32 -> bf16 once (each token row re-read by 32 N-blocks in GEMM1)
__global__ void k_cvt_x(const float* __restrict__ x, u16* __restrict__ xbf) {
  int i = blockIdx.x * 256 + threadIdx.x;   // T*H/8 threads
  const f32x4* xp = (const f32x4*)x;
  f32x4 a = xp[i * 2], b = xp[i * 2 + 1];
  b16v8 o;
  o[0] = (__bf16)a[0]; o[1] = (__bf16)a[1]; o[2] = (__bf16)a[2]; o[3] = (__bf16)a[3];
  o[4] = (__bf16)b[0]; o[5] = (__bf16)b[1]; o[6] = (__bf16)b[2]; o[7] = (__bf16)b[3];
  ((b16v8*)xbf)[i] = o;
}

// ---------------- GEMM1: h = gelu(x[tok] @ w1[e] + b1[e]) -> bf16 ----------------
// LDS layout (both A[m][k] and B[n][k], bf16, 128B rows):
//   byte(r,k) = r*128 + ((2*k) ^ ((r&7)<<4))   -- 16B-granular XOR swizzle

__global__ __launch_bounds__(256) void k_gemm1(
    const u16* __restrict__ xbf, const float* __restrict__ w1, const float* __restrict__ b1,
    const int* __restrict__ tok, const int* __restrict__ meta, u16* __restrict__ hbuf)
{
  int nt = meta[M_NT];
  int slot = blockIdx.x;
  if (slot >= nt) return;
  int e     = meta[M_TE + slot];
  int rbase = meta[M_TR + slot];
  int cbase = blockIdx.y * BN;

  alignas(16) __shared__ char LDS[32768];
  char* Alds = LDS;
  char* Blds = LDS + 16384;

  int tid = threadIdx.x;
  int lane = tid & 63;
  int wid = tid >> 6;
  int wr = wid >> 1, wc = wid & 1;

  // A staging: 4x 16B chunks/thread; chunk idx -> (row r, k-slot ks)
  const u16* aptr[4]; int awoff[4];
#pragma unroll
  for (int g = 0; g < 4; ++g) {
    int idx = tid + g * 256;
    int r = idx >> 3, ks = idx & 7;
    int t = tok[rbase + r];
    aptr[g]  = xbf + (size_t)t * H_DIM + ks * 8;
    awoff[g] = r * 128 + ((ks * 16) ^ ((r & 7) << 4));
  }
  // B staging: 4x 16B chunks/thread; chunk idx -> (col n, k-slot ks); gather 8 k's (stride F)
  const float* bptr[4]; int bwoff[4];
  const float* w1e = w1 + (size_t)e * H_DIM * F_DIM + cbase;
#pragma unroll
  for (int g = 0; g < 4; ++g) {
    int idx = tid + g * 256;
    int n = idx & 127, ks = idx >> 7;
    bptr[g]  = w1e + (size_t)(ks * 8) * F_DIM + n;
    bwoff[g] = n * 128 + ((ks * 16) ^ ((n & 7) << 4));
  }

  f32x4 acc[4][4];
#pragma unroll
  for (int m = 0; m < 4; ++m)
#pragma unroll
    for (int n = 0; n < 4; ++n) acc[m][n] = (f32x4){0.f, 0.f, 0.f, 0.f};

  for (int kt = 0; kt < H_DIM / BK; ++kt) {
    if (kt) __syncthreads();
    int kb = kt * BK;
#pragma unroll
    for (int g = 0; g < 4; ++g) {
      u16x8 v = *(const u16x8*)(aptr[g] + kb);
      *(u16x8*)(Alds + awoff[g]) = v;
    }
#pragma unroll
    for (int g = 0; g < 4; ++g) {
      const float* p = bptr[g] + (size_t)kb * F_DIM;
      b16v8 v;
#pragma unroll
      for (int j = 0; j < 8; ++j) v[j] = (__bf16)p[(size_t)j * F_DIM];
      *(b16v8*)(Blds + bwoff[g]) = v;
    }
    __syncthreads();
#pragma unroll
    for (int kk = 0; kk < 2; ++kk) {
      int kbyte = kk * 64 + ((lane >> 4) << 4);   // 2*k0
      bf16x8 af[4], bfr[4];
#pragma unroll
      for (int m = 0; m < 4; ++m) {
        int r = wr * 64 + m * 16 + (lane & 15);
        af[m] = *(const bf16x8*)(Alds + r * 128 + (kbyte ^ ((r & 7) << 4)));
      }
#pragma unroll
      for (int n = 0; n < 4; ++n) {
        int c = wc * 64 + n * 16 + (lane & 15);
        bfr[n] = *(const bf16x8*)(Blds + c * 128 + (kbyte ^ ((c & 7) << 4)));
      }
#pragma unroll
      for (int m = 0; m < 4; ++m)
#pragma unroll
        for (int n = 0; n < 4; ++n)
          acc[m][n] = __builtin_amdgcn_mfma_f32_16x16x32_bf16(af[m], bfr[n], acc[m][n], 0, 0, 0);
    }
  }

  // epilogue: bias + gelu + bf16, LDS bounce -> coalesced 16B h stores
  __syncthreads();   // all waves done reading LDS
  float bv[4];
#pragma unroll
  for (int n = 0; n < 4; ++n) bv[n] = b1[e * F_DIM + cbase + wc * 64 + n * 16 + (lane & 15)];
  char* reg = LDS + wid * 8192;   // per-wave 4 x 2KB (16 rows x 64 cols bf16 each)
#pragma unroll
  for (int m = 0; m < 4; ++m)
#pragma unroll
    for (int n = 0; n < 4; ++n)
#pragma unroll
      for (int q = 0; q < 4; ++q) {
        float v = acc[m][n][q] + bv[n];
        v = gelu_tanh(v);
        int row4 = ((lane >> 4) << 2) + q;
        int col = n * 16 + (lane & 15);
        *(__bf16*)(reg + m * 2048 + row4 * 128 + col * 2) = (__bf16)v;
      }
  __syncthreads();
#pragma unroll
  for (int q = 0; q < 8; ++q) {
    int m = q >> 1, p = q & 1;
    int byte = p * 1024 + lane * 16;
    u16x8 v = *(const u16x8*)(reg + m * 2048 + byte);
    int row  = p * 8 + (lane >> 3);
    int colb = (lane & 7) * 16;
    size_t grow = (size_t)(rbase + wr * 64 + m * 16 + row);
    size_t gcol = (size_t)(cbase + wc * 64 + (colb >> 1));
    *(u16x8*)(hbuf + grow * F_DIM + gcol) = v;
  }
}

// ---------------- GEMM2: out[tok] += wgt * (h @ w2[e] + b2[e]), split-K=2 ----------------

__global__ __launch_bounds__(256) void k_gemm2(
    const u16* __restrict__ hbuf, const float* __restrict__ w2, const float* __restrict__ b2,
    const int* __restrict__ tok, const float* __restrict__ wgt,
    const int* __restrict__ meta, float* __restrict__ out)
{
  int nt = meta[M_NT];
  int slot = blockIdx.x;
  if (slot >= nt) return;
  int e     = meta[M_TE + slot];
  int rbase = meta[M_TR + slot];
  int cbase = blockIdx.y * BN;          // H tiles (8)
  int kzb   = blockIdx.z * (F_DIM / 2); // split-K half

  alignas(16) __shared__ char LDS[32768];
  char* Alds = LDS;
  char* Blds = LDS + 16384;

  int tid = threadIdx.x;
  int lane = tid & 63;
  int wid = tid >> 6;
  int wr = wid >> 1, wc = wid & 1;

  const u16* aptr[4]; int awoff[4];
#pragma unroll
  for (int g = 0; g < 4; ++g) {
    int idx = tid + g * 256;
    int r = idx >> 3, ks = idx & 7;
    aptr[g]  = hbuf + (size_t)(rbase + r) * F_DIM + kzb + ks * 8;
    awoff[g] = r * 128 + ((ks * 16) ^ ((r & 7) << 4));
  }
  const float* bptr[4]; int bwoff[4];
  const float* w2e = w2 + (size_t)e * F_DIM * H_DIM + cbase;
#pragma unroll
  for (int g = 0; g < 4; ++g) {
    int idx = tid + g * 256;
    int n = idx & 127, ks = idx >> 7;
    bptr[g]  = w2e + (size_t)(kzb + ks * 8) * H_DIM + n;
    bwoff[g] = n * 128 + ((ks * 16) ^ ((n & 7) << 4));
  }

  f32x4 acc[4][4];
#pragma unroll
  for (int m = 0; m < 4; ++m)
#pragma unroll
    for (int n = 0; n < 4; ++n) acc[m][n] = (f32x4){0.f, 0.f, 0.f, 0.f};

  for (int kt = 0; kt < (F_DIM / 2) / BK; ++kt) {
    if (kt) __syncthreads();
    int kb = kt * BK;
#pragma unroll
    for (int g = 0; g < 4; ++g) {
      u16x8 v = *(const u16x8*)(aptr[g] + kb);
      *(u16x8*)(Alds + awoff[g]) = v;
    }
#pragma unroll
    for (int g = 0; g < 4; ++g) {
      const float* p = bptr[g] + (size_t)kb * H_DIM;
      b16v8 v;
#pragma unroll
      for (int j = 0; j < 8; ++j) v[j] = (__bf16)p[(size_t)j * H_DIM];
      *(b16v8*)(Blds + bwoff[g]) = v;
    }
    __syncthreads();
#pragma unroll
    for (int kk = 0; kk < 2; ++kk) {
      int kbyte = kk * 64 + ((lane >> 4) << 4);
      bf16x8 af[4], bfr[4];
#pragma unroll
      for (int m = 0; m < 4; ++m) {
        int r = wr * 64 + m * 16 + (lane & 15);
        af[m] = *(const bf16x8*)(Alds + r * 128 + (kbyte ^ ((r & 7) << 4)));
      }
#pragma unroll
      for (int n = 0; n < 4; ++n) {
        int c = wc * 64 + n * 16 + (lane & 15);
        bfr[n] = *(const bf16x8*)(Blds + c * 128 + (kbyte ^ ((c & 7) << 4)));
      }
#pragma unroll
      for (int m = 0; m < 4; ++m)
#pragma unroll
        for (int n = 0; n < 4; ++n)
          acc[m][n] = __builtin_amdgcn_mfma_f32_16x16x32_bf16(af[m], bfr[n], acc[m][n], 0, 0, 0);
    }
  }

  // epilogue: per-entry weight * (acc + b2) atomically into out[tok]
  bool z0 = (blockIdx.z == 0);
  float bv[4];
#pragma unroll
  for (int n = 0; n < 4; ++n)
    bv[n] = z0 ? b2[e * H_DIM + cbase + wc * 64 + n * 16 + (lane & 15)] : 0.f;
#pragma unroll
  for (int m = 0; m < 4; ++m)
#pragma unroll
    for (int q = 0; q < 4; ++q) {
      int row = wr * 64 + m * 16 + ((lane >> 4) << 2) + q;
      int grow = rbase + row;
      int t = tok[grow];
      float w = wgt[grow];
      float* op = out + (size_t)t * H_DIM + cbase + wc * 64 + (lane & 15);
#pragma unroll
      for (int n = 0; n < 4; ++n)
        atomicAdd(op + n * 16, w * (acc[m][n][q] + bv[n]));
    }
}

// ---------------- launch ----------------

extern "C" void kernel_launch(void* const* d_in, const int* in_sizes, int n_in,
                              void* d_out, int out_size, void* d_ws, size_t ws_size,
                              hipStream_t stream)
{
  const float* x       = (const float*)d_in[0];
  const float* probs   = (const float*)d_in[1];
  const int*   experts = (const int*)d_in[2];
  const float* w1      = (const float*)d_in[3];
  const float* b1      = (const float*)d_in[4];
  const float* w2      = (const float*)d_in[5];
  const float* b2      = (const float*)d_in[6];
  float* out = (float*)d_out;

  char* ws = (char*)d_ws;
  size_t off = 0;
  u16*   hbuf = (u16*)(ws + off);  off += (size_t)PADMAX * F_DIM * sizeof(u16);  // 75.5 MB
  u16*   xbf  = (u16*)(ws + off);  off += (size_t)T_NUM * H_DIM * sizeof(u16);   // 8.4 MB
  int*   tok  = (int*)(ws + off);  off += (size_t)PADMAX * sizeof(int);
  float* wgt  = (float*)(ws + off); off += (size_t)PADMAX * sizeof(float);
  int*   meta = (int*)(ws + off);  off += M_INTS * sizeof(int);
  (void)ws_size; (void)in_sizes; (void)n_in;

  hipMemsetAsync(d_out, 0, (size_t)out_size * sizeof(float), stream);
  k_init   <<<dim3((PADMAX + 255) / 256), 256, 0, stream>>>(tok, wgt, meta);
  k_count  <<<dim3(NE / 256), 256, 0, stream>>>(experts, meta);
  k_plan   <<<1, 1, 0, stream>>>(meta);
  k_scatter<<<dim3(NE / 256), 256, 0, stream>>>(experts, probs, tok, wgt, meta);
  k_cvt_x  <<<dim3(T_NUM * H_DIM / 8 / 256), 256, 0, stream>>>(x, xbf);
  k_gemm1  <<<dim3(MAXTILES, F_DIM / BN), 256, 0, stream>>>(xbf, w1, b1, tok, meta, hbuf);
  k_gemm2  <<<dim3(MAXTILES, H_DIM / BN, 2), 256, 0, stream>>>(hbuf, w2, b2, tok, wgt, meta, out);
}

// Round 2
// 358.719 us; speedup vs baseline: 1.8305x; 1.8305x over previous
//
#include <hip/hip_runtime.h>
#include <stdint.h>

// Problem constants (B=2,S=2048,H=1024,F=4096,E=8,K=2)
#define H_DIM 1024
#define F_DIM 4096
#define E_NUM 8
#define T_NUM 4096            // B*S tokens
#define NE    8192            // K * T entries
#define BM    128
#define BN    128
#define BK    64
#define MAXTILES 72           // sum_e ceil(n_e/BM) <= NE/BM + (E-1) = 71 < 72
#define PADMAX (MAXTILES*BM)  // 9216 padded entry rows

// meta[] layout (ints)
#define M_NT  0     // ntiles
#define M_PB  1     // [8]  padded base row per expert
#define M_CNT 16    // [8]  counts
#define M_CUR 24    // [8]  scatter cursors
#define M_TE  32    // [72] tile -> expert
#define M_TR  104   // [72] tile -> row base
#define M_INTS 176

typedef float  f32x4  __attribute__((ext_vector_type(4)));
typedef short  bf16x8 __attribute__((ext_vector_type(8)));   // MFMA frag: 8 bf16 bit-patterns
typedef __bf16 b16v8  __attribute__((ext_vector_type(8)));   // for fp32->bf16 conversion
typedef unsigned short u16;
typedef u16    u16x8  __attribute__((ext_vector_type(8)));

__device__ __forceinline__ float gelu_tanh(float v) {
  float u = 0.7978845608028654f * (v + 0.044715f * v * v * v);
  return v / (1.0f + __expf(-2.0f * u));
}

__device__ __forceinline__ float b2f(u16 v) {
  union { float f; unsigned u; } x; x.u = ((unsigned)v) << 16; return x.f;
}

// async global->LDS, 16B per lane; dst must be wave-uniform base (lane*16 implicit)
__device__ __forceinline__ void gl16(const void* g, void* l) {
  __builtin_amdgcn_global_load_lds(
      (const __attribute__((address_space(1))) unsigned int*)g,
      (__attribute__((address_space(3))) unsigned int*)l, 16, 0, 0);
}

// ---------------- prep kernels ----------------

__global__ void k_init(int* tok, float* wgt, int* meta) {
  int i = blockIdx.x * 256 + threadIdx.x;
  if (i < PADMAX) { tok[i] = 0; wgt[i] = 0.f; }   // padded rows: token 0, weight 0
  if (i < E_NUM) { meta[M_CNT + i] = 0; meta[M_CUR + i] = 0; }
}

__global__ void k_count(const int* __restrict__ experts, int* meta) {
  int i = blockIdx.x * 256 + threadIdx.x;   // NE threads exactly
  int e = experts[i];
  int lane = threadIdx.x & 63;
#pragma unroll
  for (int ee = 0; ee < E_NUM; ++ee) {
    unsigned long long bm = __ballot(e == ee);
    if (e == ee && lane == __builtin_ctzll(bm))
      atomicAdd(&meta[M_CNT + ee], __popcll(bm));
  }
}

__global__ void k_plan(int* meta) {
  if (threadIdx.x != 0 || blockIdx.x != 0) return;
  int pb = 0, idx = 0;
  for (int e = 0; e < E_NUM; ++e) {
    int c = meta[M_CNT + e];
    int nt = (c + BM - 1) / BM;
    meta[M_PB + e] = pb;
    for (int t = 0; t < nt; ++t) { meta[M_TE + idx] = e; meta[M_TR + idx] = pb + t * BM; ++idx; }
    pb += nt * BM;
  }
  meta[M_NT] = idx;
}

__global__ void k_scatter(const int* __restrict__ experts, const float* __restrict__ probs,
                          int* tok, float* wgt, int* entpos, int* meta) {
  int i = blockIdx.x * 256 + threadIdx.x;   // NE threads; i = k*T + t
  int e = experts[i];
  int t = i & (T_NUM - 1);
  float p = probs[i];
  int lane = threadIdx.x & 63;
#pragma unroll
  for (int ee = 0; ee < E_NUM; ++ee) {
    unsigned long long bm = __ballot(e == ee);
    if (e == ee) {
      int leader = __builtin_ctzll(bm);
      int cnt = __popcll(bm);
      int base = 0;
      if (lane == leader) base = atomicAdd(&meta[M_CUR + ee], cnt);
      base = __shfl(base, leader);
      int rank = __popcll(bm & ((1ull << lane) - 1ull));
      int pos = meta[M_PB + ee] + base + rank;
      tok[pos] = t;
      wgt[pos] = p;
      entpos[i] = pos;
    }
  }
}

// x fp32 -> bf16 (linear)
__global__ void k_cvt_x(const float* __restrict__ x, u16* __restrict__ xbf) {
  int i = blockIdx.x * 256 + threadIdx.x;   // T*H/8 threads
  const f32x4* xp = (const f32x4*)x;
  f32x4 a = xp[i * 2], b = xp[i * 2 + 1];
  b16v8 o;
  o[0] = (__bf16)a[0]; o[1] = (__bf16)a[1]; o[2] = (__bf16)a[2]; o[3] = (__bf16)a[3];
  o[4] = (__bf16)b[0]; o[5] = (__bf16)b[1]; o[6] = (__bf16)b[2]; o[7] = (__bf16)b[3];
  ((b16v8*)xbf)[i] = o;
}

// transpose+convert: W fp32 [E][R][C] -> Wt bf16 [E][C][R].  grid (C/64, R/64, E)
__global__ __launch_bounds__(256) void k_trans(const float* __restrict__ W, u16* __restrict__ Wt,
                                               int R, int C) {
  alignas(16) __shared__ char L[16384];   // 64x64 fp32, 16B-chunk XOR swizzle
  int e = blockIdx.z;
  int r0 = blockIdx.y * 64, c0 = blockIdx.x * 64;
  const float* We = W + (size_t)e * R * C;
  u16* Wte = Wt + (size_t)e * R * C;
  int tid = threadIdx.x;
#pragma unroll
  for (int it = 0; it < 4; ++it) {
    int gi = it * 256 + tid;
    int row = gi >> 4, c4 = gi & 15;
    f32x4 v = *(const f32x4*)(We + (size_t)(r0 + row) * C + c0 + c4 * 4);
    *(f32x4*)(L + row * 256 + ((c4 ^ (row & 15)) * 16)) = v;
  }
  __syncthreads();
#pragma unroll
  for (int s = 0; s < 2; ++s) {
    int chunk = s * 256 + tid;
    int c = chunk >> 3, rb = chunk & 7;
    b16v8 o;
#pragma unroll
    for (int j = 0; j < 8; ++j) {
      int r = rb * 8 + j;
      float f = *(const float*)(L + r * 256 + (((c >> 2) ^ (r & 15)) * 16) + (c & 3) * 4);
      o[j] = (__bf16)f;
    }
    *(b16v8*)(void*)(Wte + (size_t)(c0 + c) * R + r0 + rb * 8) = o;
  }
}

// ---------------- GEMM1: h = gelu(x[tok] @ w1[e] + b1[e]) -> bf16 ----------------
// LDS tiles A[m][k], B[n][k] bf16, 128B rows; chunk c of row r holds src k-chunk c^(r&7).
// Staged with global_load_lds: linear LDS dest, XOR folded into per-lane global src.

__global__ __launch_bounds__(256) void k_gemm1(
    const u16* __restrict__ xbf, const u16* __restrict__ w1t, const float* __restrict__ b1,
    const int* __restrict__ tok, const int* __restrict__ meta, u16* __restrict__ hbuf)
{
  int nt = meta[M_NT];
  int slot = blockIdx.x;
  if (slot >= nt) return;
  int e     = meta[M_TE + slot];
  int rbase = meta[M_TR + slot];
  int cbase = blockIdx.y * BN;

  alignas(16) __shared__ char LDS[32768];
  char* Alds = LDS;
  char* Blds = LDS + 16384;

  int tid = threadIdx.x;
  int lane = tid & 63;
  int wid = tid >> 6;
  int wr = wid >> 1, wc = wid & 1;
  int ks = lane & 7, r8 = lane >> 3;

  const u16* asrc[4]; const u16* bsrc[4]; char* adst[4]; char* bdst[4];
#pragma unroll
  for (int j = 0; j < 4; ++j) {
    int r = wid * 32 + j * 8 + r8;
    int t = tok[rbase + r];
    asrc[j] = xbf + (size_t)t * H_DIM + ((ks ^ (r & 7)) * 8);
    bsrc[j] = w1t + ((size_t)e * F_DIM + cbase + r) * H_DIM + ((ks ^ (r & 7)) * 8);
    adst[j] = Alds + (wid * 32 + j * 8) * 128;
    bdst[j] = Blds + (wid * 32 + j * 8) * 128;
  }

  f32x4 acc[4][4];
#pragma unroll
  for (int m = 0; m < 4; ++m)
#pragma unroll
    for (int n = 0; n < 4; ++n) acc[m][n] = (f32x4){0.f, 0.f, 0.f, 0.f};

  for (int kt = 0; kt < H_DIM / BK; ++kt) {
    int kb = kt * BK;
    if (kt) __syncthreads();
#pragma unroll
    for (int j = 0; j < 4; ++j) gl16(asrc[j] + kb, adst[j]);
#pragma unroll
    for (int j = 0; j < 4; ++j) gl16(bsrc[j] + kb, bdst[j]);
    __syncthreads();
#pragma unroll
    for (int kk = 0; kk < 2; ++kk) {
      int kbyte = kk * 64 + ((lane >> 4) << 4);
      bf16x8 af[4], bfr[4];
#pragma unroll
      for (int m = 0; m < 4; ++m) {
        int r = wr * 64 + m * 16 + (lane & 15);
        af[m] = *(const bf16x8*)(Alds + r * 128 + (kbyte ^ ((r & 7) << 4)));
      }
#pragma unroll
      for (int n = 0; n < 4; ++n) {
        int c = wc * 64 + n * 16 + (lane & 15);
        bfr[n] = *(const bf16x8*)(Blds + c * 128 + (kbyte ^ ((c & 7) << 4)));
      }
#pragma unroll
      for (int m = 0; m < 4; ++m)
#pragma unroll
        for (int n = 0; n < 4; ++n)
          acc[m][n] = __builtin_amdgcn_mfma_f32_16x16x32_bf16(af[m], bfr[n], acc[m][n], 0, 0, 0);
    }
  }

  // epilogue: bias + gelu + bf16, LDS bounce -> coalesced 16B h stores
  __syncthreads();
  float bv[4];
#pragma unroll
  for (int n = 0; n < 4; ++n) bv[n] = b1[e * F_DIM + cbase + wc * 64 + n * 16 + (lane & 15)];
  char* reg = LDS + wid * 8192;
#pragma unroll
  for (int m = 0; m < 4; ++m)
#pragma unroll
    for (int n = 0; n < 4; ++n)
#pragma unroll
      for (int q = 0; q < 4; ++q) {
        float v = acc[m][n][q] + bv[n];
        v = gelu_tanh(v);
        int row4 = ((lane >> 4) << 2) + q;
        int col = n * 16 + (lane & 15);
        *(__bf16*)(reg + m * 2048 + row4 * 128 + col * 2) = (__bf16)v;
      }
  __syncthreads();
#pragma unroll
  for (int q = 0; q < 8; ++q) {
    int m = q >> 1, p = q & 1;
    int byte = p * 1024 + lane * 16;
    u16x8 v = *(const u16x8*)(reg + m * 2048 + byte);
    int row  = p * 8 + (lane >> 3);
    int colb = (lane & 7) * 16;
    size_t grow = (size_t)(rbase + wr * 64 + m * 16 + row);
    size_t gcol = (size_t)(cbase + wc * 64 + (colb >> 1));
    *(u16x8*)(hbuf + grow * F_DIM + gcol) = v;
  }
}

// ---------------- GEMM2: y[z][r] = h[r] @ w2[e] (+ b2 if z==0), split-K=2, bf16 out ----------------

__global__ __launch_bounds__(256) void k_gemm2(
    const u16* __restrict__ hbuf, const u16* __restrict__ w2t, const float* __restrict__ b2,
    const int* __restrict__ meta, u16* __restrict__ ybuf)
{
  int nt = meta[M_NT];
  int slot = blockIdx.x;
  if (slot >= nt) return;
  int e     = meta[M_TE + slot];
  int rbase = meta[M_TR + slot];
  int cbase = blockIdx.y * BN;          // H tiles (8)
  int kzb   = blockIdx.z * (F_DIM / 2); // split-K half

  alignas(16) __shared__ char LDS[32768];
  char* Alds = LDS;
  char* Blds = LDS + 16384;

  int tid = threadIdx.x;
  int lane = tid & 63;
  int wid = tid >> 6;
  int wr = wid >> 1, wc = wid & 1;
  int ks = lane & 7, r8 = lane >> 3;

  const u16* asrc[4]; const u16* bsrc[4]; char* adst[4]; char* bdst[4];
#pragma unroll
  for (int j = 0; j < 4; ++j) {
    int r = wid * 32 + j * 8 + r8;
    asrc[j] = hbuf + (size_t)(rbase + r) * F_DIM + kzb + ((ks ^ (r & 7)) * 8);
    bsrc[j] = w2t + ((size_t)e * H_DIM + cbase + r) * F_DIM + kzb + ((ks ^ (r & 7)) * 8);
    adst[j] = Alds + (wid * 32 + j * 8) * 128;
    bdst[j] = Blds + (wid * 32 + j * 8) * 128;
  }

  f32x4 acc[4][4];
#pragma unroll
  for (int m = 0; m < 4; ++m)
#pragma unroll
    for (int n = 0; n < 4; ++n) acc[m][n] = (f32x4){0.f, 0.f, 0.f, 0.f};

  for (int kt = 0; kt < (F_DIM / 2) / BK; ++kt) {
    int kb = kt * BK;
    if (kt) __syncthreads();
#pragma unroll
    for (int j = 0; j < 4; ++j) gl16(asrc[j] + kb, adst[j]);
#pragma unroll
    for (int j = 0; j < 4; ++j) gl16(bsrc[j] + kb, bdst[j]);
    __syncthreads();
#pragma unroll
    for (int kk = 0; kk < 2; ++kk) {
      int kbyte = kk * 64 + ((lane >> 4) << 4);
      bf16x8 af[4], bfr[4];
#pragma unroll
      for (int m = 0; m < 4; ++m) {
        int r = wr * 64 + m * 16 + (lane & 15);
        af[m] = *(const bf16x8*)(Alds + r * 128 + (kbyte ^ ((r & 7) << 4)));
      }
#pragma unroll
      for (int n = 0; n < 4; ++n) {
        int c = wc * 64 + n * 16 + (lane & 15);
        bfr[n] = *(const bf16x8*)(Blds + c * 128 + (kbyte ^ ((c & 7) << 4)));
      }
#pragma unroll
      for (int m = 0; m < 4; ++m)
#pragma unroll
        for (int n = 0; n < 4; ++n)
          acc[m][n] = __builtin_amdgcn_mfma_f32_16x16x32_bf16(af[m], bfr[n], acc[m][n], 0, 0, 0);
    }
  }

  // epilogue: (+b2 if z==0), bf16, LDS bounce -> coalesced 16B stores into ybuf
  __syncthreads();
  bool z0 = (blockIdx.z == 0);
  u16* yb = ybuf + (size_t)blockIdx.z * PADMAX * H_DIM;
  float bv[4];
#pragma unroll
  for (int n = 0; n < 4; ++n)
    bv[n] = z0 ? b2[e * H_DIM + cbase + wc * 64 + n * 16 + (lane & 15)] : 0.f;
  char* reg = LDS + wid * 8192;
#pragma unroll
  for (int m = 0; m < 4; ++m)
#pragma unroll
    for (int n = 0; n < 4; ++n)
#pragma unroll
      for (int q = 0; q < 4; ++q) {
        float v = acc[m][n][q] + bv[n];
        int row4 = ((lane >> 4) << 2) + q;
        int col = n * 16 + (lane & 15);
        *(__bf16*)(reg + m * 2048 + row4 * 128 + col * 2) = (__bf16)v;
      }
  __syncthreads();
#pragma unroll
  for (int q = 0; q < 8; ++q) {
    int m = q >> 1, p = q & 1;
    int byte = p * 1024 + lane * 16;
    u16x8 v = *(const u16x8*)(reg + m * 2048 + byte);
    int row  = p * 8 + (lane >> 3);
    int colb = (lane & 7) * 16;
    size_t grow = (size_t)(rbase + wr * 64 + m * 16 + row);
    size_t gcol = (size_t)(cbase + wc * 64 + (colb >> 1));
    *(u16x8*)(yb + grow * H_DIM + gcol) = v;
  }
}

// ---------------- combine: out[t] = sum_k wgt[p_k] * (y0[p_k] + y1[p_k]) ----------------

__global__ __launch_bounds__(256) void k_combine(
    const u16* __restrict__ ybuf, const float* __restrict__ wgt,
    const int* __restrict__ entpos, float* __restrict__ out)
{
  int idx = blockIdx.x * 256 + threadIdx.x;   // T*H/8 threads
  int t = idx >> 7, hc = idx & 127;
  int p0 = entpos[t], p1 = entpos[T_NUM + t];
  float w0 = wgt[p0], w1 = wgt[p1];
  const u16x8* y0 = (const u16x8*)(ybuf);
  const u16x8* y1 = (const u16x8*)(ybuf + (size_t)PADMAX * H_DIM);
  u16x8 a = y0[(size_t)p0 * (H_DIM / 8) + hc];
  u16x8 b = y1[(size_t)p0 * (H_DIM / 8) + hc];
  u16x8 c = y0[(size_t)p1 * (H_DIM / 8) + hc];
  u16x8 d = y1[(size_t)p1 * (H_DIM / 8) + hc];
  f32x4 o0, o1;
#pragma unroll
  for (int j = 0; j < 4; ++j)
    o0[j] = w0 * (b2f(a[j]) + b2f(b[j])) + w1 * (b2f(c[j]) + b2f(d[j]));
#pragma unroll
  for (int j = 0; j < 4; ++j)
    o1[j] = w0 * (b2f(a[4 + j]) + b2f(b[4 + j])) + w1 * (b2f(c[4 + j]) + b2f(d[4 + j]));
  f32x4* op = (f32x4*)(out + (size_t)t * H_DIM + hc * 8);
  op[0] = o0;
  op[1] = o1;
}

// ---------------- launch ----------------

extern "C" void kernel_launch(void* const* d_in, const int* in_sizes, int n_in,
                              void* d_out, int out_size, void* d_ws, size_t ws_size,
                              hipStream_t stream)
{
  const float* x       = (const float*)d_in[0];
  const float* probs   = (const float*)d_in[1];
  const int*   experts = (const int*)d_in[2];
  const float* w1      = (const float*)d_in[3];
  const float* b1      = (const float*)d_in[4];
  const float* w2      = (const float*)d_in[5];
  const float* b2      = (const float*)d_in[6];
  float* out = (float*)d_out;

  char* ws = (char*)d_ws;
  size_t off = 0;
  u16*   hbuf = (u16*)(ws + off);  off += (size_t)PADMAX * F_DIM * sizeof(u16);  // 75.5 MB
  u16*   xbf  = (u16*)(ws + off);  off += (size_t)T_NUM * H_DIM * sizeof(u16);   // 8.4 MB
  u16*   w1t  = (u16*)(ws + off);  off += (size_t)E_NUM * F_DIM * H_DIM * sizeof(u16); // 67.1 MB
  u16*   w2t  = (u16*)(ws + off);  off += (size_t)E_NUM * F_DIM * H_DIM * sizeof(u16); // 67.1 MB
  int*   tok  = (int*)(ws + off);  off += (size_t)PADMAX * sizeof(int);
  float* wgt  = (float*)(ws + off); off += (size_t)PADMAX * sizeof(float);
  int*   entpos = (int*)(ws + off); off += (size_t)NE * sizeof(int);
  int*   meta = (int*)(ws + off);  off += M_INTS * sizeof(int);
  u16*   ybuf = w1t;   // alias: w1t is dead after k_gemm1; ybuf = [2][PADMAX][H] bf16 (37.7 MB)
  (void)ws_size; (void)in_sizes; (void)n_in;

  k_init   <<<dim3((PADMAX + 255) / 256), 256, 0, stream>>>(tok, wgt, meta);
  k_count  <<<dim3(NE / 256), 256, 0, stream>>>(experts, meta);
  k_plan   <<<1, 1, 0, stream>>>(meta);
  k_scatter<<<dim3(NE / 256), 256, 0, stream>>>(experts, probs, tok, wgt, entpos, meta);
  k_cvt_x  <<<dim3(T_NUM * H_DIM / 8 / 256), 256, 0, stream>>>(x, xbf);
  k_trans  <<<dim3(F_DIM / 64, H_DIM / 64, E_NUM), 256, 0, stream>>>(w1, w1t, H_DIM, F_DIM);
  k_trans  <<<dim3(H_DIM / 64, F_DIM / 64, E_NUM), 256, 0, stream>>>(w2, w2t, F_DIM, H_DIM);
  k_gemm1  <<<dim3(MAXTILES, F_DIM / BN), 256, 0, stream>>>(xbf, w1t, b1, tok, meta, hbuf);
  k_gemm2  <<<dim3(MAXTILES, H_DIM / BN, 2), 256, 0, stream>>>(hbuf, w2t, b2, meta, ybuf);
  k_combine<<<dim3(T_NUM * H_DIM / 8 / 256), 256, 0, stream>>>(ybuf, wgt, entpos, out);
}